// Round 1
// baseline (227.340 us; speedup 1.0000x reference)
//
#include <hip/hip_runtime.h>
#include <math.h>

// DVGO volume-rendering forward, round 10.
// Round-9 theory: dvgo_fwd is gather *instruction* throughput-bound (TA/L1),
// not byte-bound (HBM 40%, VALU 23%, occupancy ruled out in r8). Halve the
// vmem instruction count at identical byte traffic:
//   - z-pair corner gathers: corners (x,y,z) and (x,y,z+1) are adjacent 8 B
//     records in the z-fastest packed grid -> one dwordx4 (16 B) load fetches
//     both. Interior gathers 8 -> 4 per sample (on- and off-rays).
//     (dword-aligned dwordx4 is legal/fast on CDNA; only dword alignment is
//     required for flat/global multi-dword ops.)
//   - pair the rgb store: (r,g) as one dwordx2, b as dword. Stores 5 -> 4.
// Predicted: dvgo_fwd 56.6 -> ~40 us, FETCH/WRITE unchanged (~80/98 MB),
// hbm_gbps up proportionally. If time doesn't move at constant FETCH, the
// wall is L1 line-fill, and next round is ray sorting / brick layout.

namespace {
constexpr int   kR   = 8192;
constexpr int   kS   = 558;
constexpr int   kG   = 160;
constexpr int   kG2  = kG * kG;
constexpr int   kG3  = kG * kG * kG;
constexpr float kNear = 0.05f;
constexpr float kFar  = 6.0f;
constexpr float kStepWorld = 0.5f * (2.0f / 160.0f);  // STEPSIZE * VOXEL_SIZE
constexpr float kActShift = -13.815509557963774f;     // log(1/(1-1e-6)-1)
constexpr float kLog2e = 1.4426950408889634f;
}

typedef unsigned int nuint2 __attribute__((ext_vector_type(2)));
typedef unsigned int nuint4 __attribute__((ext_vector_type(4)));
typedef float        nfloat2 __attribute__((ext_vector_type(2)));

__device__ __forceinline__ float fexp(float x) {   // e^x
  return __builtin_amdgcn_exp2f(x * kLog2e);
}
__device__ __forceinline__ float sigmoidf_(float x) {
  return __builtin_amdgcn_rcpf(1.0f + fexp(-x));
}

// ---- repack: planar 7-channel f32 -> 7 x fp8 e4m3 (8 B/voxel) ----
__global__ __launch_bounds__(256) void repack_grids(
    const float* __restrict__ density,
    const float* __restrict__ off_c,
    const float* __restrict__ emo_c,
    nuint2* __restrict__ packed)
{
  const int v = blockIdx.x * blockDim.x + threadIdx.x;
  if (v >= kG3) return;
  const float d  = __builtin_nontemporal_load(density + v);
  const float f0 = __builtin_nontemporal_load(off_c + v);
  const float f1 = __builtin_nontemporal_load(off_c + v + kG3);
  const float f2 = __builtin_nontemporal_load(off_c + v + 2 * kG3);
  const float e0 = __builtin_nontemporal_load(emo_c + v);
  const float e1 = __builtin_nontemporal_load(emo_c + v + kG3);
  const float e2 = __builtin_nontemporal_load(emo_c + v + 2 * kG3);
  int qx = __builtin_amdgcn_cvt_pk_fp8_f32(d,  f0, 0,  false);  // bytes 0,1
  qx     = __builtin_amdgcn_cvt_pk_fp8_f32(f1, f2, qx, true);   // bytes 2,3
  int qy = __builtin_amdgcn_cvt_pk_fp8_f32(e0, e1, 0,  false);
  qy     = __builtin_amdgcn_cvt_pk_fp8_f32(e2, 0.0f, qy, true);
  nuint2 q;
  q.x = (unsigned)qx;
  q.y = (unsigned)qy;
  __builtin_nontemporal_store(q, packed + v);
}

// ---- main: one 64-lane wave per ray (fused) ----
__global__ __launch_bounds__(256) void dvgo_fwd(
    const float* __restrict__ rays_o,
    const float* __restrict__ rays_d,
    const float* __restrict__ jitter,
    const int*   __restrict__ em_modes,
    const uint2* __restrict__ packed8,   // 8 B per voxel
    float* __restrict__ out)
{
  const int tid  = blockIdx.x * blockDim.x + threadIdx.x;
  const int ray  = tid >> 6;
  const int lane = tid & 63;
  if (ray >= kR) return;

  const float ox = rays_o[ray * 3 + 0];
  const float oy = rays_o[ray * 3 + 1];
  const float oz = rays_o[ray * 3 + 2];
  const float dx = rays_d[ray * 3 + 0];
  const float dy = rays_d[ray * 3 + 1];
  const float dz = rays_d[ray * 3 + 2];
  const float jit = jitter[ray];
  const bool  on  = (em_modes[ray] == 1);

  const float vx = (dx == 0.0f) ? 1e-6f : dx;
  const float vy = (dy == 0.0f) ? 1e-6f : dy;
  const float vz = (dz == 0.0f) ? 1e-6f : dz;
  const float ivx = __builtin_amdgcn_rcpf(vx);
  const float ivy = __builtin_amdgcn_rcpf(vy);
  const float ivz = __builtin_amdgcn_rcpf(vz);
  const float rax = ( 1.0f - ox) * ivx, rbx = (-1.0f - ox) * ivx;
  const float ray_a = ( 1.0f - oy) * ivy, rby = (-1.0f - oy) * ivy;
  const float raz = ( 1.0f - oz) * ivz, rbz = (-1.0f - oz) * ivz;
  float tmin = fmaxf(fmaxf(fminf(rax, rbx), fminf(ray_a, rby)), fminf(raz, rbz));
  float tmax = fminf(fminf(fmaxf(rax, rbx), fmaxf(ray_a, rby)), fmaxf(raz, rbz));
  tmin = fminf(fmaxf(tmin, kNear), kFar);
  tmax = fminf(fmaxf(tmax, kNear), kFar);
  const bool  ray_out = (tmax <= tmin);
  const float stepc = kStepWorld *
      __builtin_amdgcn_rsqf(dx * dx + dy * dy + dz * dz);

  float* out_ainv = out;                           // [R, S+1]
  float* out_w    = out + (size_t)kR * (kS + 1);   // [R, S]
  float* out_last = out_w + (size_t)kR * kS;       // [R, 1]
  float* out_rgb  = out_last + kR;                 // [R, S, 3]
  float* out_rm   = out_rgb + (size_t)kR * kS * 3; // [R, 3]

  if (lane == 0)
    __builtin_nontemporal_store(1.0f, out_ainv + (size_t)ray * (kS + 1));

  const float c_base = on ? 1.0f : 0.5f;  // sigma(0) (+sigma(0) if on)

  float carry = 1.0f;
  float accr = 0.0f, accg = 0.0f, accb = 0.0f;
  bool dead = false;

  #pragma unroll 1
  for (int chunk = 0; chunk < (kS + 63) / 64; ++chunk) {
    const int  s      = chunk * 64 + lane;
    const bool active = (s < kS);

    if (!dead) {
      const float t  = tmin + stepc * ((float)s + jit);
      const float px = fmaf(dx, t, ox);
      const float py = fmaf(dy, t, oy);
      const float pz = fmaf(dz, t, oz);
      const bool inb = (px >= -1.0f) & (px <= 1.0f) &
                       (py >= -1.0f) & (py <= 1.0f) &
                       (pz >= -1.0f) & (pz <= 1.0f);
      const bool masked = ray_out || !inb;

      const float fx = (px + 1.0f) * 0.5f * (float)(kG - 1);
      const float fy = (py + 1.0f) * 0.5f * (float)(kG - 1);
      const float fz = (pz + 1.0f) * 0.5f * (float)(kG - 1);
      const int ix = (int)floorf(fx);
      const int iy = (int)floorf(fy);
      const int iz = (int)floorf(fz);

      const bool reach = active &&
          (ix >= -1) && (ix <= kG - 1) &&
          (iy >= -1) && (iy <= kG - 1) &&
          (iz >= -1) && (iz <= kG - 1);
      if (__ballot(reach) == 0ull) {
        dead = true;  // monotone: no later sample re-enters reach
      } else {
        const float wx = fx - (float)ix;
        const float wy = fy - (float)iy;
        const float wz = fz - (float)iz;
        const float x0 = 1.0f - wx, y0 = 1.0f - wy, z0 = 1.0f - wz;
        const float wxy00 = x0 * y0, wxy01 = x0 * wy;
        const float wxy10 = wx * y0, wxy11 = wx * wy;
        float w8[8];
        w8[0] = wxy00 * z0; w8[1] = wxy00 * wz;
        w8[2] = wxy01 * z0; w8[3] = wxy01 * wz;
        w8[4] = wxy10 * z0; w8[5] = wxy10 * wz;
        w8[6] = wxy11 * z0; w8[7] = wxy11 * wz;

        float dsum = 0.0f;
        float o0 = 0.0f, o1 = 0.0f, o2 = 0.0f;
        float e0 = 0.0f, e1 = 0.0f, e2 = 0.0f;

        const bool interior = active &&
            (ix >= 0) && (ix < kG - 1) &&
            (iy >= 0) && (iy < kG - 1) &&
            (iz >= 0) && (iz < kG - 1);

        if (interior) {
          // z-paired gathers: one 16 B load = corners (..,z) and (..,z+1).
          // q.x/q.y = record gi (dens|off / emo), q.z/q.w = record gi+1.
          const int base = (ix * kG + iy) * kG + iz;
          #pragma unroll
          for (int cc = 0; cc < 4; ++cc) {
            const int gi = base + ((cc >> 1) & 1) * kG2 + (cc & 1) * kG;
            const nuint4 q = *(const nuint4*)(packed8 + gi);
            const float w0 = w8[2 * cc + 0];
            const float w1 = w8[2 * cc + 1];
            dsum = fmaf(w0, __builtin_amdgcn_cvt_f32_fp8((int)q.x, 0),
                   fmaf(w1, __builtin_amdgcn_cvt_f32_fp8((int)q.z, 0), dsum));
            o0   = fmaf(w0, __builtin_amdgcn_cvt_f32_fp8((int)q.x, 1),
                   fmaf(w1, __builtin_amdgcn_cvt_f32_fp8((int)q.z, 1), o0));
            o1   = fmaf(w0, __builtin_amdgcn_cvt_f32_fp8((int)q.x, 2),
                   fmaf(w1, __builtin_amdgcn_cvt_f32_fp8((int)q.z, 2), o1));
            o2   = fmaf(w0, __builtin_amdgcn_cvt_f32_fp8((int)q.x, 3),
                   fmaf(w1, __builtin_amdgcn_cvt_f32_fp8((int)q.z, 3), o2));
            if (on) {
              e0 = fmaf(w0, __builtin_amdgcn_cvt_f32_fp8((int)q.y, 0),
                   fmaf(w1, __builtin_amdgcn_cvt_f32_fp8((int)q.w, 0), e0));
              e1 = fmaf(w0, __builtin_amdgcn_cvt_f32_fp8((int)q.y, 1),
                   fmaf(w1, __builtin_amdgcn_cvt_f32_fp8((int)q.w, 1), e1));
              e2 = fmaf(w0, __builtin_amdgcn_cvt_f32_fp8((int)q.y, 2),
                   fmaf(w1, __builtin_amdgcn_cvt_f32_fp8((int)q.w, 2), e2));
            }
          }
        } else if (reach) {
          #pragma unroll
          for (int c = 0; c < 8; ++c) {
            const int cx = ix + ((c >> 2) & 1);
            const int cy = iy + ((c >> 1) & 1);
            const int cz = iz + (c & 1);
            const bool valid = ((unsigned)cx < (unsigned)kG) &
                               ((unsigned)cy < (unsigned)kG) &
                               ((unsigned)cz < (unsigned)kG);
            const float wv = valid ? w8[c] : 0.0f;
            const int gx = min(max(cx, 0), kG - 1);
            const int gy = min(max(cy, 0), kG - 1);
            const int gz = min(max(cz, 0), kG - 1);
            const int gi = (gx * kG + gy) * kG + gz;
            const uint2 q = packed8[gi];
            dsum = fmaf(wv, __builtin_amdgcn_cvt_f32_fp8((int)q.x, 0), dsum);
            o0   = fmaf(wv, __builtin_amdgcn_cvt_f32_fp8((int)q.x, 1), o0);
            o1   = fmaf(wv, __builtin_amdgcn_cvt_f32_fp8((int)q.x, 2), o1);
            o2   = fmaf(wv, __builtin_amdgcn_cvt_f32_fp8((int)q.x, 3), o2);
            if (on) {
              e0 = fmaf(wv, __builtin_amdgcn_cvt_f32_fp8((int)q.y, 0), e0);
              e1 = fmaf(wv, __builtin_amdgcn_cvt_f32_fp8((int)q.y, 1), e1);
              e2 = fmaf(wv, __builtin_amdgcn_cvt_f32_fp8((int)q.y, 2), e2);
            }
          }
        }

        // p = (1+e^x)^-0.5 == exp(-softplus(x)*0.5) exactly; masked -> 1
        float p = 1.0f;
        if (active && !masked) {
          const float ex = fexp(dsum + kActShift);
          p = fmaxf(__builtin_amdgcn_rsqf(1.0f + ex), 1e-10f);
        }
        const float alpha = 1.0f - p;

        float incl = p;
        #pragma unroll
        for (int o = 1; o < 64; o <<= 1) {
          const float n = __shfl_up(incl, o, 64);
          if (lane >= o) incl *= n;
        }
        float excl = __shfl_up(incl, 1, 64);
        if (lane == 0) excl = 1.0f;
        const float ainv_prev = carry * excl;
        const float ainv_next = carry * incl;
        const float wgt = alpha * ainv_prev;
        carry *= __shfl(incl, 63, 64);

        float rr = sigmoidf_(o0);
        float gg = sigmoidf_(o1);
        float bb = sigmoidf_(o2);
        if (on) {
          rr += sigmoidf_(e0);
          gg += sigmoidf_(e1);
          bb += sigmoidf_(e2);
        }

        if (active) {
          __builtin_nontemporal_store(ainv_next,
              out_ainv + (size_t)ray * (kS + 1) + s + 1);
          __builtin_nontemporal_store(wgt, out_w + (size_t)ray * kS + s);
          const size_t rb = ((size_t)ray * kS + s) * 3;
          nfloat2 rg;
          rg.x = rr; rg.y = gg;
          __builtin_nontemporal_store(rg, (nfloat2*)(out_rgb + rb));
          __builtin_nontemporal_store(bb, out_rgb + rb + 2);
          accr = fmaf(wgt, rr, accr);
          accg = fmaf(wgt, gg, accg);
          accb = fmaf(wgt, bb, accb);
        }
        continue;  // live chunk handled
      }
    }

    // dead tail: alpha=0, p=1, sampler output 0 -> rgb consts
    if (active) {
      __builtin_nontemporal_store(carry,
          out_ainv + (size_t)ray * (kS + 1) + s + 1);
      __builtin_nontemporal_store(0.0f, out_w + (size_t)ray * kS + s);
      const size_t rb = ((size_t)ray * kS + s) * 3;
      nfloat2 cb;
      cb.x = c_base; cb.y = c_base;
      __builtin_nontemporal_store(cb, (nfloat2*)(out_rgb + rb));
      __builtin_nontemporal_store(c_base, out_rgb + rb + 2);
    }
  }

  #pragma unroll
  for (int o = 32; o > 0; o >>= 1) {
    accr += __shfl_xor(accr, o, 64);
    accg += __shfl_xor(accg, o, 64);
    accb += __shfl_xor(accb, o, 64);
  }
  if (lane == 0) {
    out_last[ray] = carry;
    out_rm[(size_t)ray * 3 + 0] = accr;
    out_rm[(size_t)ray * 3 + 1] = accg;
    out_rm[(size_t)ray * 3 + 2] = accb;
  }
}

extern "C" void kernel_launch(void* const* d_in, const int* in_sizes, int n_in,
                              void* d_out, int out_size, void* d_ws, size_t ws_size,
                              hipStream_t stream) {
  const float* rays_o  = (const float*)d_in[0];
  const float* rays_d  = (const float*)d_in[1];
  const float* jitter  = (const float*)d_in[2];
  const int*   em      = (const int*)d_in[3];
  const float* density = (const float*)d_in[4];
  const float* off_c   = (const float*)d_in[5];
  const float* emo_c   = (const float*)d_in[6];
  float* out = (float*)d_out;

  nuint2* packed = (nuint2*)d_ws;  // 32.7 MB
  (void)ws_size;

  hipLaunchKernelGGL(repack_grids, dim3((kG3 + 255) / 256), dim3(256), 0,
                     stream, density, off_c, emo_c, packed);

  const int threads = 256;
  const int blocks  = (kR * 64) / threads;  // 2048
  hipLaunchKernelGGL(dvgo_fwd, dim3(blocks), dim3(threads), 0, stream,
                     rays_o, rays_d, jitter, em, (const uint2*)packed, out);
}